// Round 12
// baseline (265.511 us; speedup 1.0000x reference)
//
#include <hip/hip_runtime.h>
#include <hip/hip_bf16.h>
#include <hip/hip_cooperative_groups.h>
#include <math.h>

namespace cg = cooperative_groups;

#define HIDDEN 256
#define K_NBR 20
#define NB 1024

typedef __bf16 bf16x8 __attribute__((ext_vector_type(8)));
typedef float f32x4 __attribute__((ext_vector_type(4)));

__device__ __forceinline__ float wave_sum(float v) {
#pragma unroll
    for (int o = 32; o > 0; o >>= 1) v += __shfl_xor(v, o, 64);
    return v;
}

__device__ __forceinline__ void gload16(const void* g, void* l) {
    __builtin_amdgcn_global_load_lds(
        (const __attribute__((address_space(1))) void*)g,
        (__attribute__((address_space(3))) void*)l, 16, 0, 0);
}

__device__ __forceinline__ int swz3(int g, int row) {
    return (g & ~7) | ((g & 7) ^ (row & 7));
}

// ================= FUSED COOPERATIVE KERNEL =================
struct AttnSmem {
    float pe[2][HIDDEN];
    float nbr[2][K_NBR][HIDDEN];
    int   nidx[2][K_NBR];
    float sc[2][K_NBR];
    float red[2][8];
};

__device__ void attn2_unit(int p, int t,
    const int* node_idx, const int* topk, const float* node_emb,
    const float* fallback, const float* w_attn, const float* gamma,
    const float* beta, __bf16* xb, void* smem)
{
    AttnSmem& S = *(AttnSmem*)smem;
    int s = t >> 8, tl = t & 255;
    int lane = tl & 63, w = tl >> 6;
    int b = p * 2 + s;

    int nid = node_idx[b];
    bool valid = nid >= 0;
    int safe = valid ? nid : 0;

    S.pe[s][tl] = valid ? node_emb[(size_t)safe * HIDDEN + tl] + 1e-3f * fallback[tl]
                        : fallback[tl];
    if (tl < K_NBR) S.nidx[s][tl] = topk[safe * K_NBR + tl];
    __syncthreads();

    for (int r = 0; r < K_NBR; ++r) {
        int gi = S.nidx[s][r];
        S.nbr[s][r][tl] = (gi >= 0) ? node_emb[(size_t)gi * HIDDEN + tl] : 0.f;
    }
    __syncthreads();

    float pe0 = S.pe[s][0];
    float wa[4];
#pragma unroll
    for (int q = 0; q < 4; ++q) wa[q] = w_attn[lane + 64 * q];
    for (int k = w; k < K_NBR; k += 4) {
        float pp = 0.f;
#pragma unroll
        for (int q = 0; q < 4; ++q) pp += S.nbr[s][k][lane + 64 * q] * wa[q];
        pp = wave_sum(pp);
        if (lane == 0) S.sc[s][k] = (S.nidx[s][k] >= 0) ? pe0 * pp : -1e9f;
    }
    __syncthreads();

    bool has_valid = false;
#pragma unroll
    for (int k = 0; k < K_NBR; ++k) has_valid |= (S.nidx[s][k] >= 0);
    float mx = -1e30f;
#pragma unroll
    for (int k = 0; k < K_NBR; ++k) mx = fmaxf(mx, S.sc[s][k]);
    float at[K_NBR];
    float sm = 0.f;
#pragma unroll
    for (int k = 0; k < K_NBR; ++k) { at[k] = expf(S.sc[s][k] - mx); sm += at[k]; }
    float inv = has_valid ? 1.f / sm : 0.f;

    float ctx = 0.f;
#pragma unroll
    for (int k = 0; k < K_NBR; ++k) ctx += (at[k] * inv) * S.nbr[s][k][tl];

    float v0 = S.pe[s][tl], v1 = ctx;
    float s1 = wave_sum(v0 + v1);
    float s2 = wave_sum(v0 * v0 + v1 * v1);
    if (lane == 0) { S.red[s][w] = s1; S.red[s][4 + w] = s2; }
    __syncthreads();
    s1 = S.red[s][0] + S.red[s][1] + S.red[s][2] + S.red[s][3];
    s2 = S.red[s][4] + S.red[s][5] + S.red[s][6] + S.red[s][7];
    float mu = s1 / 512.f;
    float var = s2 / 512.f - mu * mu;
    float rs = rsqrtf(var + 1e-5f);

    size_t base = (size_t)b * 512;
    int mask = b & 7;
    {
        int e = tl;
        int g = e >> 3, off = e & 7;
        int gp = (g & ~7) | ((g & 7) ^ mask);
        xb[base + gp * 8 + off] = (__bf16)((v0 - mu) * rs * gamma[tl] + beta[tl]);
        e = 256 + tl;
        g = e >> 3;
        gp = (g & ~7) | ((g & 7) ^ mask);
        xb[base + gp * 8 + off] = (__bf16)((v1 - mu) * rs * gamma[256 + tl] + beta[256 + tl]);
    }
    __syncthreads();
}

// 512-thread transpose unit: 128 n-rows x 32 k
__device__ void transpose_unit(const float* __restrict__ Wm, __bf16* __restrict__ WT,
                               int Kd, int Nd, int Np, int ux, int uy, int t)
{
    int n = ux * 128 + (t >> 2);
    int k0 = uy * 32 + (t & 3) * 8;
    bool ok = n < Nd;
    bf16x8 v;
#pragma unroll
    for (int j = 0; j < 8; ++j) {
        float f = ok ? __builtin_nontemporal_load(&Wm[(size_t)(k0 + j) * Nd + n]) : 0.f;
        v[j] = (__bf16)f;
    }
    if (n < Np) {
        int gp = swz3(k0 >> 3, n);
        *(bf16x8*)(WT + (size_t)n * Kd + gp * 8) = v;
    }
}

// gemm1 tile body: 64m x 128n, 8 waves (2m x 4n of 32x32), BK=64, counted vmcnt
__device__ void gemm1_tile(int bid, int t, void* smem,
    const __bf16* __restrict__ A, const __bf16* __restrict__ BT,
    const float* __restrict__ bias, __bf16* __restrict__ Cb)
{
    const int K = 512, N = 512;
    __bf16* As = (__bf16*)smem;             // [2][64*64]
    __bf16* Bs = (__bf16*)smem + 8192;      // [2][128*64]

    int lane = t & 63, wid = t >> 6;
    int wm = wid >> 2, wn = wid & 3;
    int lo = lane & 15, hi = lane >> 4;
    int m0 = (bid & 15) * 64;
    int n0 = (bid >> 4) * 128;
    int rsub = lane >> 3, kc = lane & 7;

    auto STAGE = [&](int buf, int k0) {
        gload16(A + (size_t)(m0 + wid * 8 + rsub) * K + k0 + kc * 8,
                &As[buf * 4096 + wid * 512]);
#pragma unroll
        for (int j = 0; j < 2; ++j) {
            int rb = j * 64 + wid * 8;
            gload16(BT + (size_t)(n0 + rb + rsub) * K + k0 + kc * 8,
                    &Bs[buf * 8192 + rb * 64]);
        }
    };

    f32x4 acc[2][2];
#pragma unroll
    for (int m = 0; m < 2; ++m)
#pragma unroll
        for (int n = 0; n < 2; ++n)
            acc[m][n] = (f32x4){0.f, 0.f, 0.f, 0.f};

    auto COMPUTE = [&](int buf) {
#pragma unroll
        for (int ks = 0; ks < 2; ++ks) {
            bf16x8 af[2], bfr[2];
#pragma unroll
            for (int m = 0; m < 2; ++m) {
                int r = wm * 32 + m * 16 + lo;
                af[m] = *(const bf16x8*)&As[buf * 4096 + r * 64 + (((ks * 4 + hi) ^ (r & 7)) * 8)];
            }
#pragma unroll
            for (int n = 0; n < 2; ++n) {
                int r = wn * 32 + n * 16 + lo;
                bfr[n] = *(const bf16x8*)&Bs[buf * 8192 + r * 64 + (((ks * 4 + hi) ^ (r & 7)) * 8)];
            }
#pragma unroll
            for (int m = 0; m < 2; ++m)
#pragma unroll
                for (int n = 0; n < 2; ++n)
                    acc[m][n] = __builtin_amdgcn_mfma_f32_16x16x32_bf16(
                        af[m], bfr[n], acc[m][n], 0, 0, 0);
        }
    };

    const int nt = K / 64;
    STAGE(0, 0);
    for (int tt = 0; tt < nt - 1; ++tt) {
        STAGE((tt + 1) & 1, (tt + 1) * 64);
        asm volatile("s_waitcnt vmcnt(3)" ::: "memory");
        __builtin_amdgcn_s_barrier();
        __builtin_amdgcn_sched_barrier(0);
        COMPUTE(tt & 1);
        __builtin_amdgcn_sched_barrier(0);
        __builtin_amdgcn_s_barrier();
    }
    asm volatile("s_waitcnt vmcnt(0)" ::: "memory");
    __builtin_amdgcn_s_barrier();
    __builtin_amdgcn_sched_barrier(0);
    COMPUTE((nt - 1) & 1);
    __builtin_amdgcn_s_barrier();

#pragma unroll
    for (int m = 0; m < 2; ++m) {
        int gr = m0 + wm * 32 + m * 16 + hi * 4;
#pragma unroll
        for (int n = 0; n < 2; ++n) {
            int gc = n0 + wn * 32 + n * 16 + lo;
            float bv = bias[gc];
#pragma unroll
            for (int r = 0; r < 4; ++r) {
                float v = acc[m][n][r] + bv;
                float g = v * 0.5f * (1.f + erff(v * 0.70710678118f));
                int row = gr + r;
                int gp = swz3(gc >> 3, row);
                Cb[(size_t)row * N + gp * 8 + (gc & 7)] = (__bf16)g;
            }
        }
    }
}

// gemm2 tile body: 128x128, 8 waves (2m x 4n of 64x32), BK=64, counted vmcnt (R11-proven)
__device__ void gemm2_tile(int tile, int t, void* smem,
    const __bf16* __restrict__ A, const __bf16* __restrict__ BT,
    const float* __restrict__ bias, float* __restrict__ C, int N)
{
    const int K = 512;
    __bf16* As = (__bf16*)smem;              // [2][128*64] 16KB each
    __bf16* Bs = (__bf16*)smem + 16384;

    int lane = t & 63, wid = t >> 6;
    int wm = wid >> 2, wn = wid & 3;
    int lo = lane & 15, hi = lane >> 4;

    int lid = (tile & 7) * 156 + (tile >> 3);
    int m0 = (lid & 7) * 128;
    int n0 = (lid >> 3) * 128;

    int rsub = lane >> 3, kc = lane & 7;

    auto STAGE = [&](int buf, int k0) {
#pragma unroll
        for (int j = 0; j < 2; ++j) {
            int rb = j * 64 + wid * 8;
            gload16(A + (size_t)(m0 + rb + rsub) * K + k0 + kc * 8, &As[buf * 8192 + rb * 64]);
        }
#pragma unroll
        for (int j = 0; j < 2; ++j) {
            int rb = j * 64 + wid * 8;
            gload16(BT + (size_t)(n0 + rb + rsub) * K + k0 + kc * 8, &Bs[buf * 8192 + rb * 64]);
        }
    };

    f32x4 acc[4][2];
#pragma unroll
    for (int m = 0; m < 4; ++m)
#pragma unroll
        for (int n = 0; n < 2; ++n)
            acc[m][n] = (f32x4){0.f, 0.f, 0.f, 0.f};

    auto COMPUTE = [&](int buf) {
#pragma unroll
        for (int ks = 0; ks < 2; ++ks) {
            bf16x8 af[4], bfr[2];
#pragma unroll
            for (int m = 0; m < 4; ++m) {
                int r = wm * 64 + m * 16 + lo;
                af[m] = *(const bf16x8*)&As[buf * 8192 + r * 64 + (((ks * 4 + hi) ^ (r & 7)) * 8)];
            }
#pragma unroll
            for (int n = 0; n < 2; ++n) {
                int r = wn * 32 + n * 16 + lo;
                bfr[n] = *(const bf16x8*)&Bs[buf * 8192 + r * 64 + (((ks * 4 + hi) ^ (r & 7)) * 8)];
            }
#pragma unroll
            for (int m = 0; m < 4; ++m)
#pragma unroll
                for (int n = 0; n < 2; ++n)
                    acc[m][n] = __builtin_amdgcn_mfma_f32_16x16x32_bf16(
                        af[m], bfr[n], acc[m][n], 0, 0, 0);
        }
    };

    const int nt = K / 64;
    STAGE(0, 0);
    for (int tt = 0; tt < nt - 1; ++tt) {
        STAGE((tt + 1) & 1, (tt + 1) * 64);
        asm volatile("s_waitcnt vmcnt(4)" ::: "memory");
        __builtin_amdgcn_s_barrier();
        __builtin_amdgcn_sched_barrier(0);
        COMPUTE(tt & 1);
        __builtin_amdgcn_sched_barrier(0);
        __builtin_amdgcn_s_barrier();
    }
    asm volatile("s_waitcnt vmcnt(0)" ::: "memory");
    __builtin_amdgcn_s_barrier();
    __builtin_amdgcn_sched_barrier(0);
    COMPUTE((nt - 1) & 1);
    __builtin_amdgcn_s_barrier();      // LDS safe for next tile's STAGE

#pragma unroll
    for (int m = 0; m < 4; ++m) {
        int gr = m0 + wm * 64 + m * 16 + hi * 4;
#pragma unroll
        for (int n = 0; n < 2; ++n) {
            int gc = n0 + wn * 32 + n * 16 + lo;
            if (gc < N) {
                float bv = bias[gc];
#pragma unroll
                for (int r = 0; r < 4; ++r)
                    C[(size_t)(gr + r) * N + gc] = acc[m][n][r] + bv;
            }
        }
    }
}

__global__ __launch_bounds__(512, 4) void fused_kernel(
    const int* node_idx, const int* topk, const float* node_emb,
    const float* fallback, const float* w_attn, const float* gamma,
    const float* beta, const float* W1, const float* b1,
    const float* W2, const float* b2,
    __bf16* xb, __bf16* w1t, __bf16* w2t, __bf16* h, float* out)
{
    __shared__ __align__(16) unsigned char SMEM[65536];
    int t = threadIdx.x;
    int bid = blockIdx.x;
    int nblk = gridDim.x;

    // ---- Phase 1: W2T (2496 units) | attn pairs (512) | W1T (64) ----
    for (int u = bid; u < 3072; u += nblk) {
        if (u < 2496) {
            transpose_unit(W2, w2t, 512, 19920, 19968, u % 156, u / 156, t);
        } else if (u < 3008) {
            attn2_unit(u - 2496, t, node_idx, topk, node_emb, fallback,
                       w_attn, gamma, beta, xb, SMEM);
        } else {
            int v = u - 3008;
            transpose_unit(W1, w1t, 512, 512, 512, v & 3, v >> 2, t);
        }
    }
    __threadfence();
    cg::this_grid().sync();

    // ---- Phase 2: gemm1 (64 tiles of 64x128) ----
    for (int g1 = bid; g1 < 64; g1 += nblk)
        gemm1_tile(g1, t, SMEM, xb, w1t, b1, h);
    __threadfence();
    cg::this_grid().sync();

    // ---- Phase 3: gemm2 (1248 tiles of 128x128, persistent) ----
    for (int tile = bid; tile < 1248; tile += nblk)
        gemm2_tile(tile, t, SMEM, h, w2t, b2, out, 19920);
}

// ================= Fallback path (R11, non-cooperative) =================
__device__ __forceinline__ void attn_ln_body(
    int b, int t, const int* __restrict__ node_idx, const int* __restrict__ topk,
    const float* __restrict__ node_emb, const float* __restrict__ fallback,
    const float* __restrict__ w_attn, const float* __restrict__ gamma,
    const float* __restrict__ beta, __bf16* __restrict__ xb, int swz_on,
    float* pe, float (*nbr)[HIDDEN], int* nidx, float* sc, float* red)
{
    int lane = t & 63, w = t >> 6;
    int nid = node_idx[b];
    bool valid = nid >= 0;
    int safe = valid ? nid : 0;

    pe[t] = valid ? node_emb[(size_t)safe * HIDDEN + t] + 1e-3f * fallback[t]
                  : fallback[t];
    if (t < K_NBR) nidx[t] = topk[safe * K_NBR + t];
    __syncthreads();
    for (int r = 0; r < K_NBR; ++r) {
        int gi = nidx[r];
        nbr[r][t] = (gi >= 0) ? node_emb[(size_t)gi * HIDDEN + t] : 0.f;
    }
    __syncthreads();
    float pe0 = pe[0];
    float wa[4];
#pragma unroll
    for (int q = 0; q < 4; ++q) wa[q] = w_attn[lane + 64 * q];
    for (int k = w; k < K_NBR; k += 4) {
        float p = 0.f;
#pragma unroll
        for (int q = 0; q < 4; ++q) p += nbr[k][lane + 64 * q] * wa[q];
        p = wave_sum(p);
        if (lane == 0) sc[k] = (nidx[k] >= 0) ? pe0 * p : -1e9f;
    }
    __syncthreads();
    bool has_valid = false;
#pragma unroll
    for (int k = 0; k < K_NBR; ++k) has_valid |= (nidx[k] >= 0);
    float mx = -1e30f;
#pragma unroll
    for (int k = 0; k < K_NBR; ++k) mx = fmaxf(mx, sc[k]);
    float at[K_NBR];
    float s = 0.f;
#pragma unroll
    for (int k = 0; k < K_NBR; ++k) { at[k] = expf(sc[k] - mx); s += at[k]; }
    float inv = has_valid ? 1.f / s : 0.f;
    float ctx = 0.f;
#pragma unroll
    for (int k = 0; k < K_NBR; ++k) ctx += (at[k] * inv) * nbr[k][t];
    float v0 = pe[t], v1 = ctx;
    float s1 = wave_sum(v0 + v1);
    float s2 = wave_sum(v0 * v0 + v1 * v1);
    if (lane == 0) { red[w] = s1; red[4 + w] = s2; }
    __syncthreads();
    s1 = red[0] + red[1] + red[2] + red[3];
    s2 = red[4] + red[5] + red[6] + red[7];
    float mu = s1 / 512.f;
    float var = s2 / 512.f - mu * mu;
    float rs = rsqrtf(var + 1e-5f);
    size_t base = (size_t)b * 512;
    int mask = swz_on ? (b & 7) : 0;
    {
        int e = t;
        int g = e >> 3, off = e & 7;
        int gp = (g & ~7) | ((g & 7) ^ mask);
        xb[base + gp * 8 + off] = (__bf16)((v0 - mu) * rs * gamma[t] + beta[t]);
        e = 256 + t;
        g = e >> 3;
        gp = (g & ~7) | ((g & 7) ^ mask);
        xb[base + gp * 8 + off] = (__bf16)((v1 - mu) * rs * gamma[256 + t] + beta[256 + t]);
    }
}

__device__ __forceinline__ void transpose_body(
    const float* __restrict__ Wm, __bf16* __restrict__ WT,
    int Kd, int Nd, int Np, int bx, int by, int t)
{
    int n = bx * 64 + (t >> 2);
    int k0 = by * 32 + (t & 3) * 8;
    bool ok = n < Nd;
    bf16x8 v;
#pragma unroll
    for (int j = 0; j < 8; ++j) {
        float f = ok ? Wm[(size_t)(k0 + j) * Nd + n] : 0.f;
        v[j] = (__bf16)f;
    }
    if (n < Np) {
        int gp = swz3(k0 >> 3, n);
        *(bf16x8*)(WT + (size_t)n * Kd + gp * 8) = v;
    }
}

__global__ __launch_bounds__(256) void prep_kernel(
    const int* __restrict__ node_idx, const int* __restrict__ topk,
    const float* __restrict__ node_emb, const float* __restrict__ fallback,
    const float* __restrict__ w_attn, const float* __restrict__ gamma,
    const float* __restrict__ beta, const float* __restrict__ W1,
    const float* __restrict__ W2, __bf16* __restrict__ xb,
    __bf16* __restrict__ w1t, __bf16* __restrict__ w2t)
{
    __shared__ float pe[HIDDEN];
    __shared__ float nbr[K_NBR][HIDDEN];
    __shared__ int   nidx[K_NBR];
    __shared__ float sc[K_NBR];
    __shared__ float red[8];
    int bid = blockIdx.x;
    int t = threadIdx.x;
    if (bid < 4992) { transpose_body(W2, w2t, 512, 19920, 19968, bid % 312, bid / 312, t); return; }
    bid -= 4992;
    if (bid < 128) { transpose_body(W1, w1t, 512, 512, 512, bid % 8, bid / 8, t); return; }
    bid -= 128;
    attn_ln_body(bid, t, node_idx, topk, node_emb, fallback, w_attn, gamma, beta,
                 xb, 1, pe, nbr, nidx, sc, red);
}

__global__ __launch_bounds__(256, 4) void gemm1_kernel(
    const __bf16* __restrict__ A, const __bf16* __restrict__ BT,
    const float* __restrict__ bias, __bf16* __restrict__ Cb,
    int M, int N, int K)
{
    constexpr int BK = 64;
    __shared__ __bf16 As[2][64 * BK];
    __shared__ __bf16 Bs[2][64 * BK];
    int t = threadIdx.x;
    int lane = t & 63, wid = t >> 6;
    int wm = wid >> 1, wn = wid & 1;
    int lo = lane & 15, hi = lane >> 4;
    int nwg = gridDim.x, bid = blockIdx.x;
    int cpx = nwg >> 3;
    int lid = (bid & 7) * cpx + (bid >> 3);
    int m0 = (lid & 15) * 64;
    int n0 = (lid >> 4) * 64;
    int rsub = lane >> 3, kc = lane & 7;
    auto STAGE = [&](int buf, int k0) {
#pragma unroll
        for (int j = 0; j < 2; ++j) {
            int rb = j * 32 + wid * 8;
            gload16(A + (size_t)(m0 + rb + rsub) * K + k0 + kc * 8, &As[buf][rb * BK]);
        }
#pragma unroll
        for (int j = 0; j < 2; ++j) {
            int rb = j * 32 + wid * 8;
            gload16(BT + (size_t)(n0 + rb + rsub) * K + k0 + kc * 8, &Bs[buf][rb * BK]);
        }
    };
    f32x4 acc[2][2];
#pragma unroll
    for (int m = 0; m < 2; ++m)
#pragma unroll
        for (int n = 0; n < 2; ++n) acc[m][n] = (f32x4){0.f, 0.f, 0.f, 0.f};
    auto COMPUTE = [&](int buf) {
#pragma unroll
        for (int ks = 0; ks < 2; ++ks) {
            bf16x8 af[2], bfr[2];
#pragma unroll
            for (int m = 0; m < 2; ++m) {
                int r = wm * 32 + m * 16 + lo;
                af[m] = *(const bf16x8*)&As[buf][r * BK + (((ks * 4 + hi) ^ (r & 7)) * 8)];
            }
#pragma unroll
            for (int n = 0; n < 2; ++n) {
                int r = wn * 32 + n * 16 + lo;
                bfr[n] = *(const bf16x8*)&Bs[buf][r * BK + (((ks * 4 + hi) ^ (r & 7)) * 8)];
            }
#pragma unroll
            for (int m = 0; m < 2; ++m)
#pragma unroll
                for (int n = 0; n < 2; ++n)
                    acc[m][n] = __builtin_amdgcn_mfma_f32_16x16x32_bf16(
                        af[m], bfr[n], acc[m][n], 0, 0, 0);
        }
    };
    const int nt = K / BK;
    STAGE(0, 0);
    for (int tt = 0; tt < nt - 1; ++tt) {
        STAGE((tt + 1) & 1, (tt + 1) * BK);
        asm volatile("s_waitcnt vmcnt(4)" ::: "memory");
        __builtin_amdgcn_s_barrier();
        __builtin_amdgcn_sched_barrier(0);
        COMPUTE(tt & 1);
        __builtin_amdgcn_sched_barrier(0);
        __builtin_amdgcn_s_barrier();
    }
    asm volatile("s_waitcnt vmcnt(0)" ::: "memory");
    __builtin_amdgcn_s_barrier();
    __builtin_amdgcn_sched_barrier(0);
    COMPUTE((nt - 1) & 1);
#pragma unroll
    for (int m = 0; m < 2; ++m) {
        int gr = m0 + wm * 32 + m * 16 + hi * 4;
#pragma unroll
        for (int n = 0; n < 2; ++n) {
            int gc = n0 + wn * 32 + n * 16 + lo;
            float bv = bias[gc];
#pragma unroll
            for (int r = 0; r < 4; ++r) {
                float v = acc[m][n][r] + bv;
                float g = v * 0.5f * (1.f + erff(v * 0.70710678118f));
                int row = gr + r;
                int gp = swz3(gc >> 3, row);
                Cb[(size_t)row * N + gp * 8 + (gc & 7)] = (__bf16)g;
            }
        }
    }
}

__global__ __launch_bounds__(512, 4) void gemm2_kernel(
    const __bf16* __restrict__ A, const __bf16* __restrict__ BT,
    const float* __restrict__ bias, float* __restrict__ C,
    int M, int N, int K)
{
    __shared__ __align__(16) unsigned char SMEM[65536];
    int t = threadIdx.x;
    int nwg = gridDim.x, bid = blockIdx.x;
    // single tile per block (grid == 1248)
    gemm2_tile(bid, t, SMEM, A, BT, bias, C, N);
    (void)nwg; (void)M; (void)K;
}

extern "C" void kernel_launch(void* const* d_in, const int* in_sizes, int n_in,
                              void* d_out, int out_size, void* d_ws, size_t ws_size,
                              hipStream_t stream) {
    const int*   node_idx = (const int*)d_in[0];
    const int*   topk     = (const int*)d_in[1];
    const float* node_emb = (const float*)d_in[2];
    const float* fallback = (const float*)d_in[3];
    const float* w_attn   = (const float*)d_in[4];
    const float* gamma    = (const float*)d_in[5];
    const float* beta     = (const float*)d_in[6];
    const float* W1       = (const float*)d_in[7];
    const float* b1       = (const float*)d_in[8];
    const float* W2       = (const float*)d_in[9];
    const float* b2       = (const float*)d_in[10];
    float* out = (float*)d_out;

    const int M = 1024, Kd = 512, N1 = 512, N2 = 19920;
    const int N2p = 19968;

    __bf16* xb  = (__bf16*)d_ws;
    __bf16* h   = xb + (size_t)M * Kd;
    __bf16* w1t = h + (size_t)M * Kd;
    __bf16* w2t = w1t + (size_t)N1 * Kd;
    size_t needed = ((size_t)2 * M * Kd + (size_t)N1 * Kd + (size_t)N2p * Kd) * sizeof(__bf16);

    if (ws_size >= needed) {
        // try cooperative fused launch
        int occ = 0;
        hipError_t e0 = hipOccupancyMaxActiveBlocksPerMultiprocessor(
            &occ, fused_kernel, 512, 0);
        int grid = (e0 == hipSuccess && occ > 0) ? (occ * 256 < 512 ? occ * 256 : 512) : 0;
        bool coop_ok = false;
        if (grid >= 64) {
            void* args[] = { (void*)&node_idx, (void*)&topk, (void*)&node_emb,
                             (void*)&fallback, (void*)&w_attn, (void*)&gamma,
                             (void*)&beta, (void*)&W1, (void*)&b1,
                             (void*)&W2, (void*)&b2,
                             (void*)&xb, (void*)&w1t, (void*)&w2t, (void*)&h,
                             (void*)&out };
            hipError_t e = hipLaunchCooperativeKernel(
                (const void*)fused_kernel, dim3(grid), dim3(512), args, 0, stream);
            coop_ok = (e == hipSuccess);
        }
        if (!coop_ok) {
            // R11 proven 3-kernel path
            prep_kernel<<<4992 + 128 + 1024, 256, 0, stream>>>(
                node_idx, topk, node_emb, fallback, w_attn, gamma, beta, W1, W2,
                xb, w1t, w2t);
            gemm1_kernel<<<dim3(128), 256, 0, stream>>>(
                xb, w1t, b1, h, M, N1, Kd);
            gemm2_kernel<<<dim3(1248), 512, 0, stream>>>(
                h, w2t, b2, out, M, N2, Kd);
        }
    } else {
        // minimal correct path (should not happen: ws has always been large enough)
        prep_kernel<<<4992 + 128 + 1024, 256, 0, stream>>>(
            node_idx, topk, node_emb, fallback, w_attn, gamma, beta, W1, W2,
            xb, w1t, w2t);
        gemm1_kernel<<<dim3(128), 256, 0, stream>>>(
            xb, w1t, b1, h, M, N1, Kd);
        gemm2_kernel<<<dim3(1248), 512, 0, stream>>>(
            h, w2t, b2, out, M, N2, Kd);
    }
}

// Round 14
// 75.254 us; speedup vs baseline: 3.5282x; 3.5282x over previous
//
#include <hip/hip_runtime.h>
#include <hip/hip_bf16.h>
#include <math.h>

#define HIDDEN 256
#define K_NBR 20
#define NB 1024

typedef __bf16 bf16x8 __attribute__((ext_vector_type(8)));
typedef float f32x4 __attribute__((ext_vector_type(4)));

__device__ __forceinline__ float wave_sum(float v) {
#pragma unroll
    for (int o = 32; o > 0; o >>= 1) v += __shfl_xor(v, o, 64);
    return v;
}

__device__ __forceinline__ void gload16(const void* g, void* l) {
    __builtin_amdgcn_global_load_lds(
        (const __attribute__((address_space(1))) void*)g,
        (__attribute__((address_space(3))) void*)l, 16, 0, 0);
}

// 3-bit swizzle (8-chunk window) — xb / w1t (gemm1 operands, BK=64)
__device__ __forceinline__ int swz3(int g, int row) {
    return (g & ~7) | ((g & 7) ^ (row & 7));
}
// 2-bit swizzle (4-chunk window, row bits 1-2) — h / w2t (gemm2 operands, BK=32)
__device__ __forceinline__ int swz2(int g, int row) {
    return (g & ~3) | ((g & 3) ^ ((row >> 1) & 3));
}

// ---------------- attention + LayerNorm body (writes xb with swz3) ----------------
__device__ __forceinline__ void attn_ln_body(
    int b, int t, const int* __restrict__ node_idx, const int* __restrict__ topk,
    const float* __restrict__ node_emb, const float* __restrict__ fallback,
    const float* __restrict__ w_attn, const float* __restrict__ gamma,
    const float* __restrict__ beta, __bf16* __restrict__ xb,
    float* pe, float (*nbr)[HIDDEN], int* nidx, float* sc, float* red)
{
    int lane = t & 63, w = t >> 6;
    int nid = node_idx[b];
    bool valid = nid >= 0;
    int safe = valid ? nid : 0;

    pe[t] = valid ? node_emb[(size_t)safe * HIDDEN + t] + 1e-3f * fallback[t]
                  : fallback[t];
    if (t < K_NBR) nidx[t] = topk[safe * K_NBR + t];
    __syncthreads();
    for (int r = 0; r < K_NBR; ++r) {
        int gi = nidx[r];
        nbr[r][t] = (gi >= 0) ? node_emb[(size_t)gi * HIDDEN + t] : 0.f;
    }
    __syncthreads();
    float pe0 = pe[0];
    float wa[4];
#pragma unroll
    for (int q = 0; q < 4; ++q) wa[q] = w_attn[lane + 64 * q];
    for (int k = w; k < K_NBR; k += 4) {
        float p = 0.f;
#pragma unroll
        for (int q = 0; q < 4; ++q) p += nbr[k][lane + 64 * q] * wa[q];
        p = wave_sum(p);
        if (lane == 0) sc[k] = (nidx[k] >= 0) ? pe0 * p : -1e9f;
    }
    __syncthreads();
    bool has_valid = false;
#pragma unroll
    for (int k = 0; k < K_NBR; ++k) has_valid |= (nidx[k] >= 0);
    float mx = -1e30f;
#pragma unroll
    for (int k = 0; k < K_NBR; ++k) mx = fmaxf(mx, sc[k]);
    float at[K_NBR];
    float s = 0.f;
#pragma unroll
    for (int k = 0; k < K_NBR; ++k) { at[k] = expf(sc[k] - mx); s += at[k]; }
    float inv = has_valid ? 1.f / s : 0.f;
    float ctx = 0.f;
#pragma unroll
    for (int k = 0; k < K_NBR; ++k) ctx += (at[k] * inv) * nbr[k][t];
    float v0 = pe[t], v1 = ctx;
    float s1 = wave_sum(v0 + v1);
    float s2 = wave_sum(v0 * v0 + v1 * v1);
    if (lane == 0) { red[w] = s1; red[4 + w] = s2; }
    __syncthreads();
    s1 = red[0] + red[1] + red[2] + red[3];
    s2 = red[4] + red[5] + red[6] + red[7];
    float mu = s1 / 512.f;
    float var = s2 / 512.f - mu * mu;
    float rs = rsqrtf(var + 1e-5f);
    size_t base = (size_t)b * 512;
    int mask = b & 7;
    {
        int e = t;
        int g = e >> 3, off = e & 7;
        int gp = (g & ~7) | ((g & 7) ^ mask);
        xb[base + gp * 8 + off] = (__bf16)((v0 - mu) * rs * gamma[t] + beta[t]);
        e = 256 + t;
        g = e >> 3;
        gp = (g & ~7) | ((g & 7) ^ mask);
        xb[base + gp * 8 + off] = (__bf16)((v1 - mu) * rs * gamma[256 + t] + beta[256 + t]);
    }
}

// ---------------- transpose body: W fp32 [K,N] -> WT bf16 [Np,K] pre-swizzled ---------------
__device__ __forceinline__ void transpose_body(
    const float* __restrict__ Wm, __bf16* __restrict__ WT,
    int Kd, int Nd, int Np, int bx, int by, int t, int two_bit)
{
    int n = bx * 64 + (t >> 2);
    int k0 = by * 32 + (t & 3) * 8;
    bool ok = n < Nd;
    bf16x8 v;
#pragma unroll
    for (int j = 0; j < 8; ++j) {
        float f = ok ? Wm[(size_t)(k0 + j) * Nd + n] : 0.f;
        v[j] = (__bf16)f;
    }
    if (n < Np) {
        int g = k0 >> 3;
        int gp = two_bit ? swz2(g, n) : swz3(g, n);
        *(bf16x8*)(WT + (size_t)n * Kd + gp * 8) = v;
    }
}

// ---------------- Fused prep: W2T(swz2) | W1T(swz3) | attn+LN(swz3) ----------------
__global__ __launch_bounds__(256) void prep_kernel(
    const int* __restrict__ node_idx, const int* __restrict__ topk,
    const float* __restrict__ node_emb, const float* __restrict__ fallback,
    const float* __restrict__ w_attn, const float* __restrict__ gamma,
    const float* __restrict__ beta, const float* __restrict__ W1,
    const float* __restrict__ W2, __bf16* __restrict__ xb,
    __bf16* __restrict__ w1t, __bf16* __restrict__ w2t)
{
    __shared__ float pe[HIDDEN];
    __shared__ float nbr[K_NBR][HIDDEN];
    __shared__ int   nidx[K_NBR];
    __shared__ float sc[K_NBR];
    __shared__ float red[8];
    int bid = blockIdx.x;
    int t = threadIdx.x;
    if (bid < 4992) { transpose_body(W2, w2t, 512, 19920, 19968, bid % 312, bid / 312, t, 1); return; }
    bid -= 4992;
    if (bid < 128) { transpose_body(W1, w1t, 512, 512, 512, bid % 8, bid / 8, t, 0); return; }
    bid -= 128;
    attn_ln_body(bid, t, node_idx, topk, node_emb, fallback, w_attn, gamma, beta,
                 xb, pe, nbr, nidx, sc, red);
}

// ---------------- GEMM1: 64x64 tile, 4 waves, BK=64, counted vmcnt (R11-proven) ------------
// reads swz3 (xb, w1t); writes h with swz2 (gemm2's A).
__global__ __launch_bounds__(256, 4) void gemm1_kernel(
    const __bf16* __restrict__ A, const __bf16* __restrict__ BT,
    const float* __restrict__ bias, __bf16* __restrict__ Cb,
    int M, int N, int K)
{
    constexpr int BK = 64;
    __shared__ __bf16 As[2][64 * BK];
    __shared__ __bf16 Bs[2][64 * BK];

    int t = threadIdx.x;
    int lane = t & 63;
    int wid = t >> 6;
    int wm = wid >> 1, wn = wid & 1;
    int lo = lane & 15, hi = lane >> 4;

    int nwg = gridDim.x;                // 128
    int bid = blockIdx.x;
    int cpx = nwg >> 3;
    int lid = (bid & 7) * cpx + (bid >> 3);
    int m0 = (lid & 15) * 64;
    int n0 = (lid >> 4) * 64;

    int rsub = lane >> 3, kc = lane & 7;

    auto STAGE = [&](int buf, int k0) {
#pragma unroll
        for (int j = 0; j < 2; ++j) {
            int rb = j * 32 + wid * 8;
            gload16(A + (size_t)(m0 + rb + rsub) * K + k0 + kc * 8, &As[buf][rb * BK]);
        }
#pragma unroll
        for (int j = 0; j < 2; ++j) {
            int rb = j * 32 + wid * 8;
            gload16(BT + (size_t)(n0 + rb + rsub) * K + k0 + kc * 8, &Bs[buf][rb * BK]);
        }
    };

    f32x4 acc[2][2];
#pragma unroll
    for (int m = 0; m < 2; ++m)
#pragma unroll
        for (int n = 0; n < 2; ++n) acc[m][n] = (f32x4){0.f, 0.f, 0.f, 0.f};

    auto COMPUTE = [&](int buf) {
#pragma unroll
        for (int ks = 0; ks < 2; ++ks) {
            bf16x8 af[2], bfr[2];
#pragma unroll
            for (int m = 0; m < 2; ++m) {
                int r = wm * 32 + m * 16 + lo;
                af[m] = *(const bf16x8*)&As[buf][r * BK + (((ks * 4 + hi) ^ (r & 7)) * 8)];
            }
#pragma unroll
            for (int n = 0; n < 2; ++n) {
                int r = wn * 32 + n * 16 + lo;
                bfr[n] = *(const bf16x8*)&Bs[buf][r * BK + (((ks * 4 + hi) ^ (r & 7)) * 8)];
            }
#pragma unroll
            for (int m = 0; m < 2; ++m)
#pragma unroll
                for (int n = 0; n < 2; ++n)
                    acc[m][n] = __builtin_amdgcn_mfma_f32_16x16x32_bf16(
                        af[m], bfr[n], acc[m][n], 0, 0, 0);
        }
    };

    const int nt = K / BK;
    STAGE(0, 0);
    for (int tt = 0; tt < nt - 1; ++tt) {
        STAGE((tt + 1) & 1, (tt + 1) * BK);
        asm volatile("s_waitcnt vmcnt(4)" ::: "memory");
        __builtin_amdgcn_s_barrier();
        __builtin_amdgcn_sched_barrier(0);
        COMPUTE(tt & 1);
        __builtin_amdgcn_sched_barrier(0);
        __builtin_amdgcn_s_barrier();
    }
    asm volatile("s_waitcnt vmcnt(0)" ::: "memory");
    __builtin_amdgcn_s_barrier();
    __builtin_amdgcn_sched_barrier(0);
    COMPUTE((nt - 1) & 1);

#pragma unroll
    for (int m = 0; m < 2; ++m) {
        int gr = m0 + wm * 32 + m * 16 + hi * 4;
#pragma unroll
        for (int n = 0; n < 2; ++n) {
            int gc = n0 + wn * 32 + n * 16 + lo;
            float bv = bias[gc];
#pragma unroll
            for (int r = 0; r < 4; ++r) {
                float v = acc[m][n][r] + bv;
                float g = v * 0.5f * (1.f + erff(v * 0.70710678118f));
                int row = gr + r;
                int gp = swz2(gc >> 3, row);           // swz2: consumed by gemm2 (BK=32)
                Cb[(size_t)row * N + gp * 8 + (gc & 7)] = (__bf16)g;
            }
        }
    }
}

// ---------------- GEMM2: 128x128 tile, BK=32, 2 buffers = 32 KB LDS ----------------
// 512 threads = 8 waves (2m x 4n of 64x32). 32 KB LDS + <=64 VGPR -> 4 blocks/CU
// (32 waves/CU, 100% occupancy): the one axis untested across R2-R11.
// Counted vmcnt(2): next tile's 2 loads stay in flight across compute.
__global__ __launch_bounds__(512, 8) void gemm2_kernel(
    const __bf16* __restrict__ A, const __bf16* __restrict__ BT,
    const float* __restrict__ bias, float* __restrict__ C,
    int M, int N, int K)
{
    constexpr int BK = 32;
    __shared__ __bf16 As[2][128 * BK];   // 8 KB each
    __shared__ __bf16 Bs[2][128 * BK];   // 8 KB each

    int t = threadIdx.x;
    int lane = t & 63;
    int wid = t >> 6;                    // 0..7
    int wm = wid >> 2, wn = wid & 3;     // 2m x 4n wave grid (64x32 per wave)
    int lo = lane & 15, hi = lane >> 4;  // hi = k-chunk 0..3

    int nwg = gridDim.x;                 // 1248
    int bid = blockIdx.x;
    int cpx = nwg >> 3;
    int lid = (bid & 7) * cpx + (bid >> 3);
    int m0 = (lid & 7) * 128;
    int n0 = (lid >> 3) * 128;

    int srow = t >> 2;                   // 0..127
    int ssl = t & 3;                     // 16B chunk in 64B row

    auto STAGE = [&](int buf, int tt) {
        int k0 = tt * BK;
        gload16(A + (size_t)(m0 + srow) * K + k0 + ssl * 8, &As[buf][wid * 512]);
        gload16(BT + (size_t)(n0 + srow) * K + k0 + ssl * 8, &Bs[buf][wid * 512]);
    };

    f32x4 acc[4][2];
#pragma unroll
    for (int m = 0; m < 4; ++m)
#pragma unroll
        for (int n = 0; n < 2; ++n) acc[m][n] = (f32x4){0.f, 0.f, 0.f, 0.f};

    auto COMPUTE = [&](int buf) {
        bf16x8 af[4], bfr[2];
#pragma unroll
        for (int m = 0; m < 4; ++m) {
            int r = wm * 64 + m * 16 + lo;
            af[m] = *(const bf16x8*)&As[buf][r * BK + ((hi ^ ((r >> 1) & 3)) * 8)];
        }
#pragma unroll
        for (int n = 0; n < 2; ++n) {
            int r = wn * 32 + n * 16 + lo;
            bfr[n] = *(const bf16x8*)&Bs[buf][r * BK + ((hi ^ ((r >> 1) & 3)) * 8)];
        }
#pragma unroll
        for (int m = 0; m < 4; ++m)
#pragma unroll
            for (int n = 0; n < 2; ++n)
                acc[m][n] = __builtin_amdgcn_mfma_f32_16x16x32_bf16(
                    af[m], bfr[n], acc[m][n], 0, 0, 0);
    };

    const int nt = K / BK;               // 16
    STAGE(0, 0);
    for (int tt = 0; tt < nt - 1; ++tt) {
        STAGE((tt + 1) & 1, tt + 1);
        asm volatile("s_waitcnt vmcnt(2)" ::: "memory");   // tile tt landed; tt+1 in flight
        __builtin_amdgcn_s_barrier();
        __builtin_amdgcn_sched_barrier(0);
        COMPUTE(tt & 1);
        __builtin_amdgcn_sched_barrier(0);
        __builtin_amdgcn_s_barrier();                      // buf[tt] free for restage
    }
    asm volatile("s_waitcnt vmcnt(0)" ::: "memory");
    __builtin_amdgcn_s_barrier();
    __builtin_amdgcn_sched_barrier(0);
    COMPUTE((nt - 1) & 1);

#pragma unroll
    for (int m = 0; m < 4; ++m) {
        int gr = m0 + wm * 64 + m * 16 + hi * 4;
#pragma unroll
        for (int n = 0; n < 2; ++n) {
            int gc = n0 + wn * 32 + n * 16 + lo;
            if (gc < N) {
                float bv = bias[gc];
#pragma unroll
                for (int r = 0; r < 4; ++r)
                    C[(size_t)(gr + r) * N + gc] = acc[m][n][r] + bv;
            }
        }
    }
}

extern "C" void kernel_launch(void* const* d_in, const int* in_sizes, int n_in,
                              void* d_out, int out_size, void* d_ws, size_t ws_size,
                              hipStream_t stream) {
    const int*   node_idx = (const int*)d_in[0];
    const int*   topk     = (const int*)d_in[1];
    const float* node_emb = (const float*)d_in[2];
    const float* fallback = (const float*)d_in[3];
    const float* w_attn   = (const float*)d_in[4];
    const float* gamma    = (const float*)d_in[5];
    const float* beta     = (const float*)d_in[6];
    const float* W1       = (const float*)d_in[7];
    const float* b1       = (const float*)d_in[8];
    const float* W2       = (const float*)d_in[9];
    const float* b2       = (const float*)d_in[10];
    float* out = (float*)d_out;

    const int M = 1024, Kd = 512, N1 = 512, N2 = 19920;
    const int N2p = 19968;

    __bf16* xb  = (__bf16*)d_ws;                      // [1024, 512]
    __bf16* h   = xb + (size_t)M * Kd;                // [1024, 512]
    __bf16* w1t = h + (size_t)M * Kd;                 // [512, 512]
    __bf16* w2t = w1t + (size_t)N1 * Kd;              // [19968, 512]

    prep_kernel<<<4992 + 128 + 1024, 256, 0, stream>>>(
        node_idx, topk, node_emb, fallback, w_attn, gamma, beta, W1, W2,
        xb, w1t, w2t);

    gemm1_kernel<<<dim3(128), 256, 0, stream>>>(
        xb, w1t, b1, h, M, N1, Kd);

    gemm2_kernel<<<dim3(1248), 512, 0, stream>>>(
        h, w2t, b2, out, M, N2, Kd);
    (void)ws_size;
}

// Round 15
// 69.163 us; speedup vs baseline: 3.8389x; 1.0881x over previous
//
#include <hip/hip_runtime.h>
#include <hip/hip_bf16.h>
#include <math.h>

#define HIDDEN 256
#define K_NBR 20
#define NB 1024

typedef __bf16 bf16x8 __attribute__((ext_vector_type(8)));
typedef float f32x4 __attribute__((ext_vector_type(4)));

__device__ __forceinline__ float wave_sum(float v) {
#pragma unroll
    for (int o = 32; o > 0; o >>= 1) v += __shfl_xor(v, o, 64);
    return v;
}

__device__ __forceinline__ void gload16(const void* g, void* l) {
    __builtin_amdgcn_global_load_lds(
        (const __attribute__((address_space(1))) void*)g,
        (__attribute__((address_space(3))) void*)l, 16, 0, 0);
}

// 3-bit swizzle: 16B-chunk g of row `row`, low 3 bits XOR'd with row&7
__device__ __forceinline__ int swz3(int g, int row) {
    return (g & ~7) | ((g & 7) ^ (row & 7));
}

// ---------------- attention + LayerNorm body (writes xb with swz3) ----------------
__device__ __forceinline__ void attn_ln_body(
    int b, int t, const int* __restrict__ node_idx, const int* __restrict__ topk,
    const float* __restrict__ node_emb, const float* __restrict__ fallback,
    const float* __restrict__ w_attn, const float* __restrict__ gamma,
    const float* __restrict__ beta, __bf16* __restrict__ xb,
    float* pe, float (*nbr)[HIDDEN], int* nidx, float* sc, float* red)
{
    int lane = t & 63, w = t >> 6;
    int nid = node_idx[b];
    bool valid = nid >= 0;
    int safe = valid ? nid : 0;

    pe[t] = valid ? node_emb[(size_t)safe * HIDDEN + t] + 1e-3f * fallback[t]
                  : fallback[t];
    if (t < K_NBR) nidx[t] = topk[safe * K_NBR + t];
    __syncthreads();
    for (int r = 0; r < K_NBR; ++r) {
        int gi = nidx[r];
        nbr[r][t] = (gi >= 0) ? node_emb[(size_t)gi * HIDDEN + t] : 0.f;
    }
    __syncthreads();
    float pe0 = pe[0];
    float wa[4];
#pragma unroll
    for (int q = 0; q < 4; ++q) wa[q] = w_attn[lane + 64 * q];
    for (int k = w; k < K_NBR; k += 4) {
        float p = 0.f;
#pragma unroll
        for (int q = 0; q < 4; ++q) p += nbr[k][lane + 64 * q] * wa[q];
        p = wave_sum(p);
        if (lane == 0) sc[k] = (nidx[k] >= 0) ? pe0 * p : -1e9f;
    }
    __syncthreads();
    bool has_valid = false;
#pragma unroll
    for (int k = 0; k < K_NBR; ++k) has_valid |= (nidx[k] >= 0);
    float mx = -1e30f;
#pragma unroll
    for (int k = 0; k < K_NBR; ++k) mx = fmaxf(mx, sc[k]);
    float at[K_NBR];
    float s = 0.f;
#pragma unroll
    for (int k = 0; k < K_NBR; ++k) { at[k] = expf(sc[k] - mx); s += at[k]; }
    float inv = has_valid ? 1.f / s : 0.f;
    float ctx = 0.f;
#pragma unroll
    for (int k = 0; k < K_NBR; ++k) ctx += (at[k] * inv) * nbr[k][t];
    float v0 = pe[t], v1 = ctx;
    float s1 = wave_sum(v0 + v1);
    float s2 = wave_sum(v0 * v0 + v1 * v1);
    if (lane == 0) { red[w] = s1; red[4 + w] = s2; }
    __syncthreads();
    s1 = red[0] + red[1] + red[2] + red[3];
    s2 = red[4] + red[5] + red[6] + red[7];
    float mu = s1 / 512.f;
    float var = s2 / 512.f - mu * mu;
    float rs = rsqrtf(var + 1e-5f);
    size_t base = (size_t)b * 512;
    int mask = b & 7;
    {
        int e = t;
        int g = e >> 3, off = e & 7;
        int gp = (g & ~7) | ((g & 7) ^ mask);
        xb[base + gp * 8 + off] = (__bf16)((v0 - mu) * rs * gamma[t] + beta[t]);
        e = 256 + t;
        g = e >> 3;
        gp = (g & ~7) | ((g & 7) ^ mask);
        xb[base + gp * 8 + off] = (__bf16)((v1 - mu) * rs * gamma[256 + t] + beta[256 + t]);
    }
}

// ---------------- transpose body: W fp32 [K,N] -> WT bf16 [Np,K] swz3 ---------------
__device__ __forceinline__ void transpose_body(
    const float* __restrict__ Wm, __bf16* __restrict__ WT,
    int Kd, int Nd, int Np, int bx, int by, int t)
{
    int n = bx * 64 + (t >> 2);
    int k0 = by * 32 + (t & 3) * 8;
    bool ok = n < Nd;
    bf16x8 v;
#pragma unroll
    for (int j = 0; j < 8; ++j) {
        float f = ok ? Wm[(size_t)(k0 + j) * Nd + n] : 0.f;
        v[j] = (__bf16)f;
    }
    if (n < Np) {
        int gp = swz3(k0 >> 3, n);
        *(bf16x8*)(WT + (size_t)n * Kd + gp * 8) = v;
    }
}

// ---------------- Fused prep: attn FIRST (straggler), then W1T, then W2T (uniform tail) -----
__global__ __launch_bounds__(256) void prep_kernel(
    const int* __restrict__ node_idx, const int* __restrict__ topk,
    const float* __restrict__ node_emb, const float* __restrict__ fallback,
    const float* __restrict__ w_attn, const float* __restrict__ gamma,
    const float* __restrict__ beta, const float* __restrict__ W1,
    const float* __restrict__ W2, __bf16* __restrict__ xb,
    __bf16* __restrict__ w1t, __bf16* __restrict__ w2t)
{
    __shared__ float pe[HIDDEN];
    __shared__ float nbr[K_NBR][HIDDEN];
    __shared__ int   nidx[K_NBR];
    __shared__ float sc[K_NBR];
    __shared__ float red[8];
    int bid = blockIdx.x;
    int t = threadIdx.x;
    if (bid < 1024) {
        attn_ln_body(bid, t, node_idx, topk, node_emb, fallback, w_attn, gamma,
                     beta, xb, pe, nbr, nidx, sc, red);
        return;
    }
    bid -= 1024;
    if (bid < 128) { transpose_body(W1, w1t, 512, 512, 512, bid % 8, bid / 8, t); return; }
    bid -= 128;
    transpose_body(W2, w2t, 512, 19920, 19968, bid % 312, bid / 312, t);
}

// ---------------- GEMM1: 64x64 tile, 4 waves, BK=64, counted vmcnt (R11-proven) ------------
__global__ __launch_bounds__(256, 4) void gemm1_kernel(
    const __bf16* __restrict__ A, const __bf16* __restrict__ BT,
    const float* __restrict__ bias, __bf16* __restrict__ Cb,
    int M, int N, int K)
{
    constexpr int BK = 64;
    __shared__ __bf16 As[2][64 * BK];
    __shared__ __bf16 Bs[2][64 * BK];

    int t = threadIdx.x;
    int lane = t & 63;
    int wid = t >> 6;
    int wm = wid >> 1, wn = wid & 1;
    int lo = lane & 15, hi = lane >> 4;

    int nwg = gridDim.x;                // 128
    int bid = blockIdx.x;
    int cpx = nwg >> 3;
    int lid = (bid & 7) * cpx + (bid >> 3);
    int m0 = (lid & 15) * 64;
    int n0 = (lid >> 4) * 64;

    int rsub = lane >> 3, kc = lane & 7;

    auto STAGE = [&](int buf, int k0) {
#pragma unroll
        for (int j = 0; j < 2; ++j) {
            int rb = j * 32 + wid * 8;
            gload16(A + (size_t)(m0 + rb + rsub) * K + k0 + kc * 8, &As[buf][rb * BK]);
        }
#pragma unroll
        for (int j = 0; j < 2; ++j) {
            int rb = j * 32 + wid * 8;
            gload16(BT + (size_t)(n0 + rb + rsub) * K + k0 + kc * 8, &Bs[buf][rb * BK]);
        }
    };

    f32x4 acc[2][2];
#pragma unroll
    for (int m = 0; m < 2; ++m)
#pragma unroll
        for (int n = 0; n < 2; ++n) acc[m][n] = (f32x4){0.f, 0.f, 0.f, 0.f};

    auto COMPUTE = [&](int buf) {
#pragma unroll
        for (int ks = 0; ks < 2; ++ks) {
            bf16x8 af[2], bfr[2];
#pragma unroll
            for (int m = 0; m < 2; ++m) {
                int r = wm * 32 + m * 16 + lo;
                af[m] = *(const bf16x8*)&As[buf][r * BK + (((ks * 4 + hi) ^ (r & 7)) * 8)];
            }
#pragma unroll
            for (int n = 0; n < 2; ++n) {
                int r = wn * 32 + n * 16 + lo;
                bfr[n] = *(const bf16x8*)&Bs[buf][r * BK + (((ks * 4 + hi) ^ (r & 7)) * 8)];
            }
#pragma unroll
            for (int m = 0; m < 2; ++m)
#pragma unroll
                for (int n = 0; n < 2; ++n)
                    acc[m][n] = __builtin_amdgcn_mfma_f32_16x16x32_bf16(
                        af[m], bfr[n], acc[m][n], 0, 0, 0);
        }
    };

    const int nt = K / BK;
    STAGE(0, 0);
    for (int tt = 0; tt < nt - 1; ++tt) {
        STAGE((tt + 1) & 1, (tt + 1) * BK);
        asm volatile("s_waitcnt vmcnt(4)" ::: "memory");
        __builtin_amdgcn_s_barrier();
        __builtin_amdgcn_sched_barrier(0);
        COMPUTE(tt & 1);
        __builtin_amdgcn_sched_barrier(0);
        __builtin_amdgcn_s_barrier();
    }
    asm volatile("s_waitcnt vmcnt(0)" ::: "memory");
    __builtin_amdgcn_s_barrier();
    __builtin_amdgcn_sched_barrier(0);
    COMPUTE((nt - 1) & 1);

#pragma unroll
    for (int m = 0; m < 2; ++m) {
        int gr = m0 + wm * 32 + m * 16 + hi * 4;
#pragma unroll
        for (int n = 0; n < 2; ++n) {
            int gc = n0 + wn * 32 + n * 16 + lo;
            float bv = bias[gc];
#pragma unroll
            for (int r = 0; r < 4; ++r) {
                float v = acc[m][n][r] + bv;
                float g = v * 0.5f * (1.f + erff(v * 0.70710678118f));
                int row = gr + r;
                int gp = swz3(gc >> 3, row);
                Cb[(size_t)row * N + gp * 8 + (gc & 7)] = (__bf16)g;
            }
        }
    }
}

// ---------------- GEMM2: 64x128 tile, BK=64, 8 waves (2m x 4n of 32x32) ----------------
// 48 KB LDS -> 3 blocks/CU (24 waves/CU); grid 2496 -> 3.25 cohorts of 768 slots
// (vs 1248/512 = 2.44 -> ceil 3 at T: halved T shrinks tail quantization loss).
// R11 counted-vmcnt loop; swz3 operands; fragment indexing identical to gemm1 (proven).
__global__ __launch_bounds__(512, 6) void gemm2_kernel(
    const __bf16* __restrict__ A, const __bf16* __restrict__ BT,
    const float* __restrict__ bias, float* __restrict__ C,
    int M, int N, int K)
{
    constexpr int BK = 64;
    __shared__ __bf16 As[2][64 * BK];    // 8 KB each
    __shared__ __bf16 Bs[2][128 * BK];   // 16 KB each

    int t = threadIdx.x;
    int lane = t & 63;
    int wid = t >> 6;                    // 0..7
    int wm = wid >> 2, wn = wid & 3;     // 2m x 4n wave grid, wave tile 32x32
    int lo = lane & 15, hi = lane >> 4;

    int nwg = gridDim.x;                 // 2496
    int bid = blockIdx.x;
    int cpx = nwg >> 3;                  // 312
    int lid = (bid & 7) * cpx + (bid >> 3);
    int m0 = (lid & 15) * 64;            // 16 m-panels
    int n0 = (lid >> 4) * 128;           // 156 n-panels

    int rsub = lane >> 3, kc = lane & 7;

    auto STAGE = [&](int buf, int k0) {
        // A: 64 rows, one 8-row chunk per wave
        gload16(A + (size_t)(m0 + wid * 8 + rsub) * K + k0 + kc * 8,
                &As[buf][(wid * 8) * BK]);
        // B: 128 rows, two 8-row chunks per wave
#pragma unroll
        for (int j = 0; j < 2; ++j) {
            int rb = j * 64 + wid * 8;
            gload16(BT + (size_t)(n0 + rb + rsub) * K + k0 + kc * 8, &Bs[buf][rb * BK]);
        }
    };

    f32x4 acc[2][2];
#pragma unroll
    for (int m = 0; m < 2; ++m)
#pragma unroll
        for (int n = 0; n < 2; ++n) acc[m][n] = (f32x4){0.f, 0.f, 0.f, 0.f};

    auto COMPUTE = [&](int buf) {
#pragma unroll
        for (int ks = 0; ks < 2; ++ks) {
            bf16x8 af[2], bfr[2];
#pragma unroll
            for (int m = 0; m < 2; ++m) {
                int r = wm * 32 + m * 16 + lo;
                af[m] = *(const bf16x8*)&As[buf][r * BK + (((ks * 4 + hi) ^ (r & 7)) * 8)];
            }
#pragma unroll
            for (int n = 0; n < 2; ++n) {
                int r = wn * 32 + n * 16 + lo;
                bfr[n] = *(const bf16x8*)&Bs[buf][r * BK + (((ks * 4 + hi) ^ (r & 7)) * 8)];
            }
#pragma unroll
            for (int m = 0; m < 2; ++m)
#pragma unroll
                for (int n = 0; n < 2; ++n)
                    acc[m][n] = __builtin_amdgcn_mfma_f32_16x16x32_bf16(
                        af[m], bfr[n], acc[m][n], 0, 0, 0);
        }
    };

    const int nt = K / BK;               // 8
    STAGE(0, 0);
    for (int tt = 0; tt < nt - 1; ++tt) {
        STAGE((tt + 1) & 1, (tt + 1) * BK);
        asm volatile("s_waitcnt vmcnt(3)" ::: "memory");   // tile tt landed; tt+1 in flight
        __builtin_amdgcn_s_barrier();
        __builtin_amdgcn_sched_barrier(0);
        COMPUTE(tt & 1);
        __builtin_amdgcn_sched_barrier(0);
        __builtin_amdgcn_s_barrier();                      // buf[tt] free for restage
    }
    asm volatile("s_waitcnt vmcnt(0)" ::: "memory");
    __builtin_amdgcn_s_barrier();
    __builtin_amdgcn_sched_barrier(0);
    COMPUTE((nt - 1) & 1);

#pragma unroll
    for (int m = 0; m < 2; ++m) {
        int gr = m0 + wm * 32 + m * 16 + hi * 4;
#pragma unroll
        for (int n = 0; n < 2; ++n) {
            int gc = n0 + wn * 32 + n * 16 + lo;
            if (gc < N) {
                float bv = bias[gc];
#pragma unroll
                for (int r = 0; r < 4; ++r)
                    C[(size_t)(gr + r) * N + gc] = acc[m][n][r] + bv;
            }
        }
    }
}

extern "C" void kernel_launch(void* const* d_in, const int* in_sizes, int n_in,
                              void* d_out, int out_size, void* d_ws, size_t ws_size,
                              hipStream_t stream) {
    const int*   node_idx = (const int*)d_in[0];
    const int*   topk     = (const int*)d_in[1];
    const float* node_emb = (const float*)d_in[2];
    const float* fallback = (const float*)d_in[3];
    const float* w_attn   = (const float*)d_in[4];
    const float* gamma    = (const float*)d_in[5];
    const float* beta     = (const float*)d_in[6];
    const float* W1       = (const float*)d_in[7];
    const float* b1       = (const float*)d_in[8];
    const float* W2       = (const float*)d_in[9];
    const float* b2       = (const float*)d_in[10];
    float* out = (float*)d_out;

    const int M = 1024, Kd = 512, N1 = 512, N2 = 19920;

    __bf16* xb  = (__bf16*)d_ws;                      // [1024, 512]
    __bf16* h   = xb + (size_t)M * Kd;                // [1024, 512]
    __bf16* w1t = h + (size_t)M * Kd;                 // [512, 512]
    __bf16* w2t = w1t + (size_t)N1 * Kd;              // [19968, 512]

    // attn (0..1023) | W1T (1024..1151) | W2T (1152..6143)
    prep_kernel<<<1024 + 128 + 4992, 256, 0, stream>>>(
        node_idx, topk, node_emb, fallback, w_attn, gamma, beta, W1, W2,
        xb, w1t, w2t);

    gemm1_kernel<<<dim3(128), 256, 0, stream>>>(
        xb, w1t, b1, h, M, N1, Kd);

    // 16m x 156n = 2496 blocks, 64x128 tile, 3 blocks/CU
    gemm2_kernel<<<dim3(2496), 512, 0, stream>>>(
        h, w2t, b2, out, M, N2, Kd);
    (void)ws_size;
}